// Round 7
// baseline (513.679 us; speedup 1.0000x reference)
//
#include <hip/hip_runtime.h>
#include <hip/hip_bf16.h>
#include <math.h>

#define N_TOK 4096
#define CDIM 1024
#define HDIM 2752
#define NEXP 8

typedef __bf16 bf16_t;
typedef __bf16 bf16x8 __attribute__((ext_vector_type(8)));
typedef float f32x4 __attribute__((ext_vector_type(4)));

__device__ __forceinline__ void gload_lds16(const void* g, void* l) {
  __builtin_amdgcn_global_load_lds(
      (const __attribute__((address_space(1))) unsigned int*)g,
      (__attribute__((address_space(3))) unsigned int*)l, 16, 0, 0);
}

// bijective XCD chunk swizzle (m204)
__device__ __forceinline__ int xcd_swz(int orig, int nwg) {
  int q = nwg >> 3, r = nwg & 7;
  int xcd = orig & 7, lin = orig >> 3;
  return (xcd < r ? xcd * (q + 1) : r * (q + 1) + (xcd - r) * q) + lin;
}

// ---------------- generic f32 -> bf16 cast (elems % 1024 == 0) ----------------
__global__ void moe_cast(const float* __restrict__ in, bf16_t* __restrict__ outp) {
  size_t i = (size_t)blockIdx.x * 256 + threadIdx.x;
  float4 v = ((const float4*)in)[i];
  union { bf16_t b[4]; unsigned long long u; } pk;
  pk.b[0] = (bf16_t)v.x; pk.b[1] = (bf16_t)v.y; pk.b[2] = (bf16_t)v.z; pk.b[3] = (bf16_t)v.w;
  ((unsigned long long*)outp)[i] = pk.u;
}

// ---------------- gating: logits (f64), top-2, softmax, fused x->bf16 cast ----------------
__global__ void moe_gating(const float* __restrict__ x, const float* __restrict__ gw,
                           int* __restrict__ top_i, float* __restrict__ top_w,
                           float* __restrict__ probs_tok, bf16_t* __restrict__ xb) {
  const int wid = threadIdx.x >> 6, lane = threadIdx.x & 63;
  const int n = blockIdx.x * 4 + wid;
  const float* xr = x + (size_t)n * CDIM;
  float xv[16];
  for (int j = 0; j < 16; j += 4)
    *(float4*)&xv[j] = *(const float4*)(xr + lane * 16 + j);
  {
    union { bf16_t b[4]; unsigned long long u; } pk;
    unsigned long long* dst = (unsigned long long*)(xb + (size_t)n * CDIM + lane * 16);
    for (int j = 0; j < 16; j += 4) {
      pk.b[0] = (bf16_t)xv[j]; pk.b[1] = (bf16_t)xv[j+1];
      pk.b[2] = (bf16_t)xv[j+2]; pk.b[3] = (bf16_t)xv[j+3];
      dst[j >> 2] = pk.u;
    }
  }
  double part[NEXP];
  for (int e = 0; e < NEXP; ++e) {
    const float* gr = gw + e * CDIM + lane * 16;
    double s = 0.0;
    for (int j = 0; j < 16; j += 4) {
      float4 g = *(const float4*)(gr + j);
      s += (double)xv[j] * g.x + (double)xv[j+1] * g.y + (double)xv[j+2] * g.z + (double)xv[j+3] * g.w;
    }
    part[e] = s;
  }
  for (int off = 32; off; off >>= 1)
    for (int e = 0; e < NEXP; ++e) part[e] += __shfl_xor(part[e], off);
  if (lane == 0) {
    int i0 = 0; double l0 = part[0];
    for (int e = 1; e < NEXP; ++e) if (part[e] > l0) { l0 = part[e]; i0 = e; }
    int i1 = -1; double l1 = -1e300;
    for (int e = 0; e < NEXP; ++e) if (e != i0 && part[e] > l1) { l1 = part[e]; i1 = e; }
    double ed = exp(l1 - l0);
    float w0 = (float)(1.0 / (1.0 + ed));
    float w1 = (float)(ed / (1.0 + ed));
    top_i[2*n] = i0; top_i[2*n+1] = i1;
    top_w[2*n] = w0; top_w[2*n+1] = w1;
    double Z = 0.0, pe[NEXP];
    for (int e = 0; e < NEXP; ++e) { pe[e] = exp(part[e] - l0); Z += pe[e]; }
    for (int e = 0; e < NEXP; ++e) probs_tok[(size_t)n * NEXP + e] = (float)(pe[e] / Z);
  }
}

// ---------------- deterministic reduce ----------------
__global__ void moe_reduce(const float* __restrict__ probs_tok, const int* __restrict__ top_i,
                           int* __restrict__ cnts, float* __restrict__ probs_sum) {
  const int e = blockIdx.x, t = threadIdx.x;
  float s = 0.f; int c = 0;
  for (int n = t; n < N_TOK; n += 256) {
    s += probs_tok[(size_t)n * NEXP + e];
    c += (top_i[2*n] == e) + (top_i[2*n+1] == e);
  }
  __shared__ float ls[256]; __shared__ int lc[256];
  ls[t] = s; lc[t] = c; __syncthreads();
  for (int o = 128; o; o >>= 1) {
    if (t < o) { ls[t] += ls[t+o]; lc[t] += lc[t+o]; }
    __syncthreads();
  }
  if (t == 0) { cnts[e] = lc[0]; probs_sum[e] = ls[0]; }
}

// ---------------- prefix offsets + aux loss ----------------
__global__ void moe_prefix_aux(const int* __restrict__ cnts, int* __restrict__ offs,
                               int* __restrict__ cursors, const float* __restrict__ probs_sum,
                               float* __restrict__ out_aux) {
  if (threadIdx.x == 0) {
    int o = 0;
    for (int e = 0; e < NEXP; ++e) { offs[e] = o; o += cnts[e]; }
    double aux = 0.0;
    for (int e = 0; e < NEXP; ++e) aux += (double)cnts[e] * (double)probs_sum[e];
    out_aux[0] = (float)(0.01 * aux / ((double)N_TOK * (double)N_TOK));
  }
  if (threadIdx.x < NEXP) cursors[threadIdx.x] = 0;
}

// ---------------- scatter: wave-aggregated atomics ----------------
__global__ void moe_scatter(const int* __restrict__ top_i, const float* __restrict__ top_w,
                            const int* __restrict__ offs, int* __restrict__ cursors,
                            int* __restrict__ rowlist, float* __restrict__ wlist,
                            int* __restrict__ pair_pos) {
  const int wid = threadIdx.x >> 6, lane = threadIdx.x & 63;
  const int n = (blockIdx.x * 4 + wid) * 64 + lane;
  const unsigned long long lt = ((unsigned long long)1 << lane) - 1;
  const int e0 = top_i[2*n], e1 = top_i[2*n + 1];
  const float w0 = top_w[2*n], w1 = top_w[2*n + 1];
  for (int e = 0; e < NEXP; ++e) {
    unsigned long long m0 = __ballot(e0 == e);
    unsigned long long m1 = __ballot(e1 == e);
    int tot = __popcll(m0) + __popcll(m1);
    int base = 0;
    if (lane == 0 && tot) base = atomicAdd(&cursors[e], tot);
    base = __shfl(base, 0);
    if (e0 == e) {
      int p = offs[e] + base + __popcll(m0 & lt);
      rowlist[p] = n; wlist[p] = w0; pair_pos[2*n] = p;
    }
    if (e1 == e) {
      int p = offs[e] + base + __popcll(m0) + __popcll(m1 & lt);
      rowlist[p] = n; wlist[p] = w1; pair_pos[2*n + 1] = p;
    }
  }
}

// ================= pipelined gate+up GEMM =================
// BM=256, cols 64 x {G,U} (B-tile 128 rows), BK=64. 512 thr / 8 waves (4m x 2n).
// Triple-buffered LDS, 2-tile prefetch, counted vmcnt(6), T2 XOR swizzle, setprio.
__global__ __launch_bounds__(512, 2) void moe_gu(
    const bf16_t* __restrict__ xb,
    const bf16_t* __restrict__ Wg_r, const bf16_t* __restrict__ Wu_r,
    const bf16_t* __restrict__ Wg_s, const bf16_t* __restrict__ Wu_s,
    bf16_t* __restrict__ hout,
    const int* __restrict__ rowlist, const int* __restrict__ offs,
    const int* __restrict__ cnts) {
  const int z = blockIdx.z;
  const bool routed = z < NEXP;
  const int wg = xcd_swz(blockIdx.x, (N_TOK / 256) * (HDIM / 64));
  const int ym = wg & 15, xn = wg >> 4;      // m-block fastest
  int cnt, hbase, loff = 0;
  const bf16_t *Wg, *Wu;
  if (routed) {
    cnt = cnts[z]; loff = offs[z]; hbase = loff;
    if (ym * 256 >= cnt) return;
    Wg = Wg_r + (size_t)z * HDIM * CDIM;
    Wu = Wu_r + (size_t)z * HDIM * CDIM;
  } else {
    cnt = N_TOK; hbase = 2 * N_TOK;
    Wg = Wg_s; Wu = Wu_s;
  }
  const int m0 = ym * 256, n0 = xn * 64;

  __shared__ alignas(16) bf16_t lA[3][256 * 64];   // 96 KB
  __shared__ alignas(16) bf16_t lB[3][128 * 64];   // 48 KB

  const int tid = threadIdx.x, wid = tid >> 6, lane = tid & 63;
  const int wm = wid >> 1, wn = wid & 1;
  const int fr = lane & 15, hi = lane >> 4;
  const int sx = (fr & 7) << 4;                    // read-side XOR (bytes)

  // staging pointers: chunk = r*512+tid; row=chunk>>3, seg=chunk&7; source col
  // pre-swizzled (seg^row&7) so linear gload_lds dest == swizzled layout.
  const bf16_t* gA[4];
#pragma unroll
  for (int r = 0; r < 4; ++r) {
    int chunk = r * 512 + tid, row = chunk >> 3, seg = chunk & 7;
    int segp = seg ^ (row & 7);
    int mrow = m0 + row, tok;
    if (routed) { int mm = mrow < cnt ? mrow : cnt - 1; tok = rowlist[loff + mm]; }
    else tok = mrow;
    gA[r] = xb + (size_t)tok * CDIM + segp * 8;
  }
  const bf16_t* gB[2];
#pragma unroll
  for (int r = 0; r < 2; ++r) {
    int chunk = r * 512 + tid, row = chunk >> 3, seg = chunk & 7;
    int segp = seg ^ (row & 7);
    gB[r] = (row < 64 ? Wg + (size_t)(n0 + row) * CDIM
                      : Wu + (size_t)(n0 + row - 64) * CDIM) + segp * 8;
  }
  const int dW = wid * 64 * 16;   // wave chunk-base bytes within a round

#define GU_STAGE0(t, b) do { \
    gload_lds16(gA[0] + (t) * 64, (char*)lA[b] + dW); \
    gload_lds16(gA[1] + (t) * 64, (char*)lA[b] + 8192 + dW); \
    gload_lds16(gB[0] + (t) * 64, (char*)lB[b] + dW); } while (0)
#define GU_STAGE1(t, b) do { \
    gload_lds16(gA[2] + (t) * 64, (char*)lA[b] + 16384 + dW); \
    gload_lds16(gA[3] + (t) * 64, (char*)lA[b] + 24576 + dW); \
    gload_lds16(gB[1] + (t) * 64, (char*)lB[b] + 8192 + dW); } while (0)

  f32x4 accG[4][2] = {}; f32x4 accU[4][2] = {};

  GU_STAGE0(0, 0); GU_STAGE1(0, 0);
  GU_STAGE0(1, 1); GU_STAGE1(1, 1);

  const int NT = CDIM / 64;  // 16
  int bb = 0;
  for (int t = 0; t < NT; ++t) {
    if (t + 1 < NT) asm volatile("s_waitcnt vmcnt(6)" ::: "memory");
    else            asm volatile("s_waitcnt vmcnt(0)" ::: "memory");
    __builtin_amdgcn_sched_barrier(0);
    __builtin_amdgcn_s_barrier();
    __builtin_amdgcn_sched_barrier(0);
    const char* cA = (const char*)lA[bb];
    const char* cB = (const char*)lB[bb];
    const int bn = (bb + 2 >= 3) ? bb - 1 : bb + 2;
    const bool pf = (t + 2 < NT);
#pragma unroll
    for (int kk = 0; kk < 2; ++kk) {
      const int kby = kk * 64 + hi * 16;
      bf16x8 a[4], bg[2], bu[2];
#pragma unroll
      for (int i = 0; i < 4; ++i)
        a[i] = *(const bf16x8*)(cA + (wm * 64 + i * 16 + fr) * 128 + (kby ^ sx));
#pragma unroll
      for (int j = 0; j < 2; ++j) {
        bg[j] = *(const bf16x8*)(cB + (wn * 32 + j * 16 + fr) * 128 + (kby ^ sx));
        bu[j] = *(const bf16x8*)(cB + (64 + wn * 32 + j * 16 + fr) * 128 + (kby ^ sx));
      }
      if (pf) { if (kk == 0) GU_STAGE0(t + 2, bn); else GU_STAGE1(t + 2, bn); }
      __builtin_amdgcn_s_barrier();
      asm volatile("s_waitcnt lgkmcnt(0)" ::: "memory");
      __builtin_amdgcn_sched_barrier(0);
      __builtin_amdgcn_s_setprio(1);
#pragma unroll
      for (int i = 0; i < 4; ++i)
#pragma unroll
        for (int j = 0; j < 2; ++j) {
          accG[i][j] = __builtin_amdgcn_mfma_f32_16x16x32_bf16(a[i], bg[j], accG[i][j], 0, 0, 0);
          accU[i][j] = __builtin_amdgcn_mfma_f32_16x16x32_bf16(a[i], bu[j], accU[i][j], 0, 0, 0);
        }
      __builtin_amdgcn_s_setprio(0);
    }
    bb = (bb + 1 == 3) ? 0 : bb + 1;
  }
  // SwiGLU epilogue -> bf16 h
#pragma unroll
  for (int i = 0; i < 4; ++i)
#pragma unroll
    for (int j = 0; j < 2; ++j)
#pragma unroll
      for (int r = 0; r < 4; ++r) {
        int lm = wm * 64 + i * 16 + hi * 4 + r;
        if (routed && m0 + lm >= cnt) continue;
        float g = accG[i][j][r], u = accU[i][j][r];
        float hv = (g / (1.f + __expf(-g))) * u;
        hout[(size_t)(hbase + m0 + lm) * HDIM + n0 + wn * 32 + j * 16 + fr] = (bf16_t)hv;
      }
#undef GU_STAGE0
#undef GU_STAGE1
}

// ================= pipelined down GEMM =================
// BM=256, BN=128, BK=64. 512 thr / 8 waves (4m x 2n), acc[4][4]. Same schedule.
__global__ __launch_bounds__(512, 2) void moe_down(
    const bf16_t* __restrict__ hin, const bf16_t* __restrict__ Wd_r,
    const bf16_t* __restrict__ Wd_s,
    float* __restrict__ outp, float* __restrict__ eo,
    const float* __restrict__ wlist,
    const int* __restrict__ offs, const int* __restrict__ cnts) {
  const int z = blockIdx.z;
  const bool routed = z < NEXP;
  const int wg = xcd_swz(blockIdx.x, (N_TOK / 256) * (CDIM / 128));
  const int ym = wg & 15, xn = wg >> 4;
  int cnt, hbase;
  const bf16_t* Wd;
  if (routed) {
    cnt = cnts[z]; hbase = offs[z];
    if (ym * 256 >= cnt) return;
    Wd = Wd_r + (size_t)z * CDIM * HDIM;
  } else {
    cnt = N_TOK; hbase = 2 * N_TOK;
    Wd = Wd_s;
  }
  const int m0 = ym * 256, n0 = xn * 128;

  __shared__ alignas(16) bf16_t lA[3][256 * 64];   // 96 KB
  __shared__ alignas(16) bf16_t lB[3][128 * 64];   // 48 KB

  const int tid = threadIdx.x, wid = tid >> 6, lane = tid & 63;
  const int wm = wid >> 1, wn = wid & 1;
  const int fr = lane & 15, hi = lane >> 4;
  const int sx = (fr & 7) << 4;

  const bf16_t* gA[4];
#pragma unroll
  for (int r = 0; r < 4; ++r) {
    int chunk = r * 512 + tid, row = chunk >> 3, seg = chunk & 7;
    int segp = seg ^ (row & 7);
    int mrow = m0 + row;
    int mm = (routed && mrow >= cnt) ? cnt - 1 : mrow;
    gA[r] = hin + (size_t)(hbase + mm) * HDIM + segp * 8;
  }
  const bf16_t* gB[2];
#pragma unroll
  for (int r = 0; r < 2; ++r) {
    int chunk = r * 512 + tid, row = chunk >> 3, seg = chunk & 7;
    int segp = seg ^ (row & 7);
    gB[r] = Wd + (size_t)(n0 + row) * HDIM + segp * 8;
  }
  const int dW = wid * 64 * 16;

#define DN_STAGE0(t, b) do { \
    gload_lds16(gA[0] + (t) * 64, (char*)lA[b] + dW); \
    gload_lds16(gA[1] + (t) * 64, (char*)lA[b] + 8192 + dW); \
    gload_lds16(gB[0] + (t) * 64, (char*)lB[b] + dW); } while (0)
#define DN_STAGE1(t, b) do { \
    gload_lds16(gA[2] + (t) * 64, (char*)lA[b] + 16384 + dW); \
    gload_lds16(gA[3] + (t) * 64, (char*)lA[b] + 24576 + dW); \
    gload_lds16(gB[1] + (t) * 64, (char*)lB[b] + 8192 + dW); } while (0)

  f32x4 acc[4][4] = {};

  DN_STAGE0(0, 0); DN_STAGE1(0, 0);
  DN_STAGE0(1, 1); DN_STAGE1(1, 1);

  const int NT = HDIM / 64;  // 43
  int bb = 0;
  for (int t = 0; t < NT; ++t) {
    if (t + 1 < NT) asm volatile("s_waitcnt vmcnt(6)" ::: "memory");
    else            asm volatile("s_waitcnt vmcnt(0)" ::: "memory");
    __builtin_amdgcn_sched_barrier(0);
    __builtin_amdgcn_s_barrier();
    __builtin_amdgcn_sched_barrier(0);
    const char* cA = (const char*)lA[bb];
    const char* cB = (const char*)lB[bb];
    const int bn = (bb + 2 >= 3) ? bb - 1 : bb + 2;
    const bool pf = (t + 2 < NT);
#pragma unroll
    for (int kk = 0; kk < 2; ++kk) {
      const int kby = kk * 64 + hi * 16;
      bf16x8 a[4], b[4];
#pragma unroll
      for (int i = 0; i < 4; ++i)
        a[i] = *(const bf16x8*)(cA + (wm * 64 + i * 16 + fr) * 128 + (kby ^ sx));
#pragma unroll
      for (int j = 0; j < 4; ++j)
        b[j] = *(const bf16x8*)(cB + (wn * 64 + j * 16 + fr) * 128 + (kby ^ sx));
      if (pf) { if (kk == 0) DN_STAGE0(t + 2, bn); else DN_STAGE1(t + 2, bn); }
      __builtin_amdgcn_s_barrier();
      asm volatile("s_waitcnt lgkmcnt(0)" ::: "memory");
      __builtin_amdgcn_sched_barrier(0);
      __builtin_amdgcn_s_setprio(1);
#pragma unroll
      for (int i = 0; i < 4; ++i)
#pragma unroll
        for (int j = 0; j < 4; ++j)
          acc[i][j] = __builtin_amdgcn_mfma_f32_16x16x32_bf16(a[i], b[j], acc[i][j], 0, 0, 0);
      __builtin_amdgcn_s_setprio(0);
    }
    bb = (bb + 1 == 3) ? 0 : bb + 1;
  }
#pragma unroll
  for (int i = 0; i < 4; ++i)
#pragma unroll
    for (int j = 0; j < 4; ++j)
#pragma unroll
      for (int r = 0; r < 4; ++r) {
        int lm = wm * 64 + i * 16 + hi * 4 + r;
        if (routed && m0 + lm >= cnt) continue;
        float v = acc[i][j][r];
        int col = n0 + wn * 64 + j * 16 + fr;
        if (routed) {
          int pos = hbase + m0 + lm;
          eo[(size_t)pos * CDIM + col] = v * wlist[pos];
        } else {
          outp[(size_t)(m0 + lm) * CDIM + col] = v;
        }
      }
#undef DN_STAGE0
#undef DN_STAGE1
}

// ---------------- combine ----------------
__global__ void moe_combine(float* __restrict__ outp, const float* __restrict__ eo,
                            const int* __restrict__ pair_pos) {
  size_t i4 = (size_t)blockIdx.x * 256 + threadIdx.x;
  int n = (int)(i4 >> 8);
  int c4 = (int)(i4 & 255);
  int p0 = pair_pos[2*n], p1 = pair_pos[2*n + 1];
  const float4* eo4 = (const float4*)eo;
  float4 a = ((const float4*)outp)[i4];
  float4 b = eo4[(size_t)p0 * 256 + c4];
  float4 c = eo4[(size_t)p1 * 256 + c4];
  float4 r;
  r.x = a.x + b.x + c.x; r.y = a.y + b.y + c.y;
  r.z = a.z + b.z + c.z; r.w = a.w + b.w + c.w;
  ((float4*)outp)[i4] = r;
}

extern "C" void kernel_launch(void* const* d_in, const int* in_sizes, int n_in,
                              void* d_out, int out_size, void* d_ws, size_t ws_size,
                              hipStream_t stream) {
  const float* x   = (const float*)d_in[0];
  const float* gw  = (const float*)d_in[1];
  const float* egw = (const float*)d_in[2];
  const float* euw = (const float*)d_in[3];
  const float* edw = (const float*)d_in[4];
  const float* sgw = (const float*)d_in[5];
  const float* suw = (const float*)d_in[6];
  const float* sdw = (const float*)d_in[7];
  float* out = (float*)d_out;

  char* ws = (char*)d_ws;
  size_t off = 0;
  auto alloc = [&](size_t bytes) -> void* {
    void* p = ws + off; off = (off + bytes + 255) & ~(size_t)255; return p;
  };
  const size_t EW = (size_t)NEXP * HDIM * CDIM;
  const size_t SW = (size_t)HDIM * CDIM;
  bf16_t* xb    = (bf16_t*)alloc((size_t)N_TOK * CDIM * 2);
  bf16_t* egw_b = (bf16_t*)alloc(EW * 2);
  bf16_t* euw_b = (bf16_t*)alloc(EW * 2);
  bf16_t* edw_b = (bf16_t*)alloc(EW * 2);
  bf16_t* sgw_b = (bf16_t*)alloc(SW * 2);
  bf16_t* suw_b = (bf16_t*)alloc(SW * 2);
  bf16_t* sdw_b = (bf16_t*)alloc(SW * 2);
  bf16_t* h     = (bf16_t*)alloc((size_t)(3 * N_TOK + 256) * HDIM * 2);
  float*  eo    = (float*)alloc((size_t)2 * N_TOK * CDIM * 4);
  int*    ctrl  = (int*)alloc(256);
  int* cnts = ctrl; int* cursors = ctrl + 8; int* offs = ctrl + 16;
  float* probs_sum = (float*)(ctrl + 24);
  int*   top_i    = (int*)alloc((size_t)N_TOK * 2 * 4);
  float* top_w    = (float*)alloc((size_t)N_TOK * 2 * 4);
  int*   pair_pos = (int*)alloc((size_t)N_TOK * 2 * 4);
  int*   rowlist  = (int*)alloc((size_t)2 * N_TOK * 4);
  float* wlist    = (float*)alloc((size_t)2 * N_TOK * 4);
  float* probs_tok = (float*)alloc((size_t)N_TOK * NEXP * 4);

  moe_cast<<<(int)(EW / 1024), 256, 0, stream>>>(egw, egw_b);
  moe_cast<<<(int)(EW / 1024), 256, 0, stream>>>(euw, euw_b);
  moe_cast<<<(int)(EW / 1024), 256, 0, stream>>>(edw, edw_b);
  moe_cast<<<(int)(SW / 1024), 256, 0, stream>>>(sgw, sgw_b);
  moe_cast<<<(int)(SW / 1024), 256, 0, stream>>>(suw, suw_b);
  moe_cast<<<(int)(SW / 1024), 256, 0, stream>>>(sdw, sdw_b);

  moe_gating<<<1024, 256, 0, stream>>>(x, gw, top_i, top_w, probs_tok, xb);
  moe_reduce<<<NEXP, 256, 0, stream>>>(probs_tok, top_i, cnts, probs_sum);
  moe_prefix_aux<<<1, 64, 0, stream>>>(cnts, offs, cursors, probs_sum, out + (size_t)N_TOK * CDIM);
  moe_scatter<<<16, 256, 0, stream>>>(top_i, top_w, offs, cursors, rowlist, wlist, pair_pos);

  // gate+up: 16 m-blocks x 43 n-panels (m fastest + XCD swizzle); z = 8 routed + shared
  moe_gu<<<dim3((N_TOK / 256) * (HDIM / 64), 1, NEXP + 1), 512, 0, stream>>>(
      xb, egw_b, euw_b, sgw_b, suw_b, h, rowlist, offs, cnts);
  // down: 16 m-blocks x 8 n-panels; z = 8 routed + shared
  moe_down<<<dim3((N_TOK / 256) * (CDIM / 128), 1, NEXP + 1), 512, 0, stream>>>(
      h, edw_b, sdw_b, out, eo, wlist, offs, cnts);
  moe_combine<<<4096, 256, 0, stream>>>(out, eo, pair_pos);
}

// Round 8
// 483.283 us; speedup vs baseline: 1.0629x; 1.0629x over previous
//
#include <hip/hip_runtime.h>
#include <hip/hip_bf16.h>
#include <math.h>

#define N_TOK 4096
#define CDIM 1024
#define HDIM 2752
#define NEXP 8

typedef __bf16 bf16_t;
typedef __bf16 bf16x8 __attribute__((ext_vector_type(8)));
typedef float f32x4 __attribute__((ext_vector_type(4)));

__device__ __forceinline__ void gload_lds16(const void* g, void* l) {
  __builtin_amdgcn_global_load_lds(
      (const __attribute__((address_space(1))) unsigned int*)g,
      (__attribute__((address_space(3))) unsigned int*)l, 16, 0, 0);
}

// ---------------- fused f32 -> bf16 cast over 6 tensors ----------------
struct Cast6 {
  const float* src[6];
  bf16_t* dst[6];
  int start[7];   // cumulative block starts; 1024 floats per block
};
__global__ void moe_cast6(Cast6 c) {
  int b = blockIdx.x;
  int k = 0;
#pragma unroll
  for (int i = 0; i < 5; ++i) k += (b >= c.start[i + 1]);
  size_t i4 = (size_t)(b - c.start[k]) * 256 + threadIdx.x;  // float4 index
  float4 v = ((const float4*)c.src[k])[i4];
  union { bf16_t b4[4]; unsigned long long u; } pk;
  pk.b4[0] = (bf16_t)v.x; pk.b4[1] = (bf16_t)v.y;
  pk.b4[2] = (bf16_t)v.z; pk.b4[3] = (bf16_t)v.w;
  ((unsigned long long*)c.dst[k])[i4] = pk.u;
}

// ---------------- gating: logits (f64), top-2, softmax, fused x->bf16 cast ----------------
__global__ void moe_gating(const float* __restrict__ x, const float* __restrict__ gw,
                           int* __restrict__ top_i, float* __restrict__ top_w,
                           float* __restrict__ probs_tok, bf16_t* __restrict__ xb) {
  const int wid = threadIdx.x >> 6, lane = threadIdx.x & 63;
  const int n = blockIdx.x * 4 + wid;
  const float* xr = x + (size_t)n * CDIM;
  float xv[16];
  for (int j = 0; j < 16; j += 4)
    *(float4*)&xv[j] = *(const float4*)(xr + lane * 16 + j);
  {
    union { bf16_t b[4]; unsigned long long u; } pk;
    unsigned long long* dst = (unsigned long long*)(xb + (size_t)n * CDIM + lane * 16);
    for (int j = 0; j < 16; j += 4) {
      pk.b[0] = (bf16_t)xv[j]; pk.b[1] = (bf16_t)xv[j+1];
      pk.b[2] = (bf16_t)xv[j+2]; pk.b[3] = (bf16_t)xv[j+3];
      dst[j >> 2] = pk.u;
    }
  }
  double part[NEXP];
  for (int e = 0; e < NEXP; ++e) {
    const float* gr = gw + e * CDIM + lane * 16;
    double s = 0.0;
    for (int j = 0; j < 16; j += 4) {
      float4 g = *(const float4*)(gr + j);
      s += (double)xv[j] * g.x + (double)xv[j+1] * g.y + (double)xv[j+2] * g.z + (double)xv[j+3] * g.w;
    }
    part[e] = s;
  }
  for (int off = 32; off; off >>= 1)
    for (int e = 0; e < NEXP; ++e) part[e] += __shfl_xor(part[e], off);
  if (lane == 0) {
    int i0 = 0; double l0 = part[0];
    for (int e = 1; e < NEXP; ++e) if (part[e] > l0) { l0 = part[e]; i0 = e; }
    int i1 = -1; double l1 = -1e300;
    for (int e = 0; e < NEXP; ++e) if (e != i0 && part[e] > l1) { l1 = part[e]; i1 = e; }
    double ed = exp(l1 - l0);
    float w0 = (float)(1.0 / (1.0 + ed));
    float w1 = (float)(ed / (1.0 + ed));
    top_i[2*n] = i0; top_i[2*n+1] = i1;
    top_w[2*n] = w0; top_w[2*n+1] = w1;
    double Z = 0.0, pe[NEXP];
    for (int e = 0; e < NEXP; ++e) { pe[e] = exp(part[e] - l0); Z += pe[e]; }
    for (int e = 0; e < NEXP; ++e) probs_tok[(size_t)n * NEXP + e] = (float)(pe[e] / Z);
  }
}

// ---------------- deterministic reduce ----------------
__global__ void moe_reduce(const float* __restrict__ probs_tok, const int* __restrict__ top_i,
                           int* __restrict__ cnts, float* __restrict__ probs_sum) {
  const int e = blockIdx.x, t = threadIdx.x;
  float s = 0.f; int c = 0;
  for (int n = t; n < N_TOK; n += 256) {
    s += probs_tok[(size_t)n * NEXP + e];
    c += (top_i[2*n] == e) + (top_i[2*n+1] == e);
  }
  __shared__ float ls[256]; __shared__ int lc[256];
  ls[t] = s; lc[t] = c; __syncthreads();
  for (int o = 128; o; o >>= 1) {
    if (t < o) { ls[t] += ls[t+o]; lc[t] += lc[t+o]; }
    __syncthreads();
  }
  if (t == 0) { cnts[e] = lc[0]; probs_sum[e] = ls[0]; }
}

// ---------------- prefix offsets + aux loss ----------------
__global__ void moe_prefix_aux(const int* __restrict__ cnts, int* __restrict__ offs,
                               int* __restrict__ cursors, const float* __restrict__ probs_sum,
                               float* __restrict__ out_aux) {
  if (threadIdx.x == 0) {
    int o = 0;
    for (int e = 0; e < NEXP; ++e) { offs[e] = o; o += cnts[e]; }
    double aux = 0.0;
    for (int e = 0; e < NEXP; ++e) aux += (double)cnts[e] * (double)probs_sum[e];
    out_aux[0] = (float)(0.01 * aux / ((double)N_TOK * (double)N_TOK));
  }
  if (threadIdx.x < NEXP) cursors[threadIdx.x] = 0;
}

// ---------------- scatter: wave-aggregated atomics ----------------
__global__ void moe_scatter(const int* __restrict__ top_i, const float* __restrict__ top_w,
                            const int* __restrict__ offs, int* __restrict__ cursors,
                            int* __restrict__ rowlist, float* __restrict__ wlist) {
  const int wid = threadIdx.x >> 6, lane = threadIdx.x & 63;
  const int n = (blockIdx.x * 4 + wid) * 64 + lane;
  const unsigned long long lt = ((unsigned long long)1 << lane) - 1;
  const int e0 = top_i[2*n], e1 = top_i[2*n + 1];
  const float w0 = top_w[2*n], w1 = top_w[2*n + 1];
  for (int e = 0; e < NEXP; ++e) {
    unsigned long long m0 = __ballot(e0 == e);
    unsigned long long m1 = __ballot(e1 == e);
    int tot = __popcll(m0) + __popcll(m1);
    int base = 0;
    if (lane == 0 && tot) base = atomicAdd(&cursors[e], tot);
    base = __shfl(base, 0);
    if (e0 == e) {
      int p = offs[e] + base + __popcll(m0 & lt);
      rowlist[p] = n; wlist[p] = w0;
    }
    if (e1 == e) {
      int p = offs[e] + base + __popcll(m0) + __popcll(m1 & lt);
      rowlist[p] = n; wlist[p] = w1;
    }
  }
}

// ---------------- gate+up GEMM (R5-exact): BM=128, 64 h-cols, B = [Wg(64); Wu(64)] ----------------
// 4 waves; wave w owns m-rows [w*32, w*32+32), all 64 cols, both G and U.
// grid: x = n-panel (fastest), y = m-block, z = expert (8) / shared (z==8)
__launch_bounds__(256)
__global__ void moe_gu(const bf16_t* __restrict__ xb,
                       const bf16_t* __restrict__ Wg_r, const bf16_t* __restrict__ Wu_r,
                       const bf16_t* __restrict__ Wg_s, const bf16_t* __restrict__ Wu_s,
                       bf16_t* __restrict__ hout,
                       const int* __restrict__ rowlist, const int* __restrict__ offs,
                       const int* __restrict__ cnts) {
  const int z = blockIdx.z;
  const bool routed = z < NEXP;
  int cnt, hbase, loff = 0;
  const bf16_t *Wg, *Wu;
  if (routed) {
    cnt = cnts[z]; loff = offs[z]; hbase = loff;
    if ((int)blockIdx.y * 128 >= cnt) return;
    Wg = Wg_r + (size_t)z * HDIM * CDIM;
    Wu = Wu_r + (size_t)z * HDIM * CDIM;
  } else {
    cnt = N_TOK; hbase = 2 * N_TOK;   // shared h rows at [8192, 12288)
    Wg = Wg_s; Wu = Wu_s;
  }
  const int m0 = blockIdx.y * 128, n0 = blockIdx.x * 64;

  __shared__ alignas(16) bf16_t lA[128 * 64];   // 16 KB
  __shared__ alignas(16) bf16_t lB[128 * 64];   // 16 KB: rows 0-63 = Wg, 64-127 = Wu

  const int tid = threadIdx.x, wid = tid >> 6, lane = tid & 63;
  const int r8 = lane >> 3, c8 = lane & 7;
  const int fr = lane & 15, hi = lane >> 4;

  const bf16_t* gA[4];
  for (int i = 0; i < 4; ++i) {
    int r = wid * 32 + i * 8 + r8;
    int tok;
    if (routed) { int mm = m0 + r < cnt ? m0 + r : cnt - 1; tok = rowlist[loff + mm]; }
    else tok = m0 + r;
    gA[i] = xb + (size_t)tok * CDIM + c8 * 8;
  }
  const bf16_t* gB[4];
  for (int i = 0; i < 4; ++i) {
    int br = wid * 32 + i * 8 + r8;
    gB[i] = (br < 64 ? Wg + (size_t)(n0 + br) * CDIM
                     : Wu + (size_t)(n0 + br - 64) * CDIM) + c8 * 8;
  }

  f32x4 accG[2][4] = {}; f32x4 accU[2][4] = {};

  for (int kt = 0; kt < CDIM / 64; ++kt) {
    if (kt) __syncthreads();
    for (int i = 0; i < 4; ++i) gload_lds16(gA[i] + kt * 64, lA + (wid * 32 + i * 8) * 64);
    for (int i = 0; i < 4; ++i) gload_lds16(gB[i] + kt * 64, lB + (wid * 32 + i * 8) * 64);
    __syncthreads();
    for (int kk = 0; kk < 2; ++kk) {
      const int kb = kk * 32 + hi * 8;
      bf16x8 a[2], bg[4], bu[4];
      for (int i = 0; i < 2; ++i) a[i] = *(const bf16x8*)(lA + (wid * 32 + i * 16 + fr) * 64 + kb);
      for (int j = 0; j < 4; ++j) {
        bg[j] = *(const bf16x8*)(lB + (j * 16 + fr) * 64 + kb);
        bu[j] = *(const bf16x8*)(lB + (64 + j * 16 + fr) * 64 + kb);
      }
      for (int i = 0; i < 2; ++i)
        for (int j = 0; j < 4; ++j) {
          accG[i][j] = __builtin_amdgcn_mfma_f32_16x16x32_bf16(a[i], bg[j], accG[i][j], 0, 0, 0);
          accU[i][j] = __builtin_amdgcn_mfma_f32_16x16x32_bf16(a[i], bu[j], accU[i][j], 0, 0, 0);
        }
    }
  }
  // SwiGLU epilogue -> bf16 h
  for (int i = 0; i < 2; ++i)
    for (int j = 0; j < 4; ++j)
      for (int r = 0; r < 4; ++r) {
        int lm = wid * 32 + i * 16 + hi * 4 + r;
        if (routed && m0 + lm >= cnt) continue;
        float g = accG[i][j][r], u = accU[i][j][r];
        float hv = (g / (1.f + __expf(-g))) * u;
        hout[(size_t)(hbase + m0 + lm) * HDIM + n0 + j * 16 + fr] = (bf16_t)hv;
      }
}

// ---------------- down GEMM (R5 structure): BM=128, BN=128, BK=64, 2x2 waves ----------------
// Epilogue: atomicAdd into out (shared plain sum; routed scaled by wlist, token-indexed).
__launch_bounds__(256)
__global__ void moe_down(const bf16_t* __restrict__ hin, const bf16_t* __restrict__ Wd_r,
                         const bf16_t* __restrict__ Wd_s,
                         float* __restrict__ outp,
                         const float* __restrict__ wlist, const int* __restrict__ rowlist,
                         const int* __restrict__ offs, const int* __restrict__ cnts) {
  const int z = blockIdx.z;
  const bool routed = z < NEXP;
  int cnt, hbase;
  const bf16_t* Wd;
  if (routed) {
    cnt = cnts[z]; hbase = offs[z];
    if ((int)blockIdx.y * 128 >= cnt) return;
    Wd = Wd_r + (size_t)z * CDIM * HDIM;
  } else {
    cnt = N_TOK; hbase = 2 * N_TOK;
    Wd = Wd_s;
  }
  const int m0 = blockIdx.y * 128, n0 = blockIdx.x * 128;

  __shared__ alignas(16) bf16_t lA[128 * 64];   // 16 KB
  __shared__ alignas(16) bf16_t lB[128 * 64];   // 16 KB

  const int tid = threadIdx.x, wid = tid >> 6, lane = tid & 63;
  const int wm = wid >> 1, wn = wid & 1;
  const int r8 = lane >> 3, c8 = lane & 7;
  const int fr = lane & 15, hi = lane >> 4;

  const bf16_t* gA[4];
  for (int i = 0; i < 4; ++i) {
    int r = wid * 32 + i * 8 + r8;
    int mm = (routed && m0 + r >= cnt) ? cnt - 1 : m0 + r;
    gA[i] = hin + (size_t)(hbase + mm) * HDIM + c8 * 8;
  }
  const bf16_t* gB[4];
  for (int i = 0; i < 4; ++i) {
    int br = wid * 32 + i * 8 + r8;
    gB[i] = Wd + (size_t)(n0 + br) * HDIM + c8 * 8;
  }

  f32x4 acc[4][4] = {};

  for (int kt = 0; kt < HDIM / 64; ++kt) {
    if (kt) __syncthreads();
    for (int i = 0; i < 4; ++i) gload_lds16(gA[i] + kt * 64, lA + (wid * 32 + i * 8) * 64);
    for (int i = 0; i < 4; ++i) gload_lds16(gB[i] + kt * 64, lB + (wid * 32 + i * 8) * 64);
    __syncthreads();
    for (int kk = 0; kk < 2; ++kk) {
      const int kb = kk * 32 + hi * 8;
      bf16x8 a[4], b[4];
      for (int i = 0; i < 4; ++i) a[i] = *(const bf16x8*)(lA + (wm * 64 + i * 16 + fr) * 64 + kb);
      for (int j = 0; j < 4; ++j) b[j] = *(const bf16x8*)(lB + (wn * 64 + j * 16 + fr) * 64 + kb);
      for (int i = 0; i < 4; ++i)
        for (int j = 0; j < 4; ++j)
          acc[i][j] = __builtin_amdgcn_mfma_f32_16x16x32_bf16(a[i], b[j], acc[i][j], 0, 0, 0);
    }
  }
  for (int i = 0; i < 4; ++i)
    for (int j = 0; j < 4; ++j)
      for (int r = 0; r < 4; ++r) {
        int lm = wm * 64 + i * 16 + hi * 4 + r;
        if (routed && m0 + lm >= cnt) continue;
        float v = acc[i][j][r];
        int col = n0 + wn * 64 + j * 16 + fr;
        if (routed) {
          int pos = hbase + m0 + lm;
          int tok = rowlist[pos];
          atomicAdd(&outp[(size_t)tok * CDIM + col], v * wlist[pos]);
        } else {
          atomicAdd(&outp[(size_t)(m0 + lm) * CDIM + col], v);
        }
      }
}

extern "C" void kernel_launch(void* const* d_in, const int* in_sizes, int n_in,
                              void* d_out, int out_size, void* d_ws, size_t ws_size,
                              hipStream_t stream) {
  const float* x   = (const float*)d_in[0];
  const float* gw  = (const float*)d_in[1];
  const float* egw = (const float*)d_in[2];
  const float* euw = (const float*)d_in[3];
  const float* edw = (const float*)d_in[4];
  const float* sgw = (const float*)d_in[5];
  const float* suw = (const float*)d_in[6];
  const float* sdw = (const float*)d_in[7];
  float* out = (float*)d_out;

  char* ws = (char*)d_ws;
  size_t off = 0;
  auto alloc = [&](size_t bytes) -> void* {
    void* p = ws + off; off = (off + bytes + 255) & ~(size_t)255; return p;
  };
  const size_t EW = (size_t)NEXP * HDIM * CDIM;   // 22,544,384
  const size_t SW = (size_t)HDIM * CDIM;          // 2,818,048
  bf16_t* xb    = (bf16_t*)alloc((size_t)N_TOK * CDIM * 2);
  bf16_t* egw_b = (bf16_t*)alloc(EW * 2);
  bf16_t* euw_b = (bf16_t*)alloc(EW * 2);
  bf16_t* edw_b = (bf16_t*)alloc(EW * 2);
  bf16_t* sgw_b = (bf16_t*)alloc(SW * 2);
  bf16_t* suw_b = (bf16_t*)alloc(SW * 2);
  bf16_t* sdw_b = (bf16_t*)alloc(SW * 2);
  bf16_t* h     = (bf16_t*)alloc((size_t)(3 * N_TOK + 256) * HDIM * 2);
  int*    ctrl  = (int*)alloc(256);
  int* cnts = ctrl; int* cursors = ctrl + 8; int* offs = ctrl + 16;
  float* probs_sum = (float*)(ctrl + 24);
  int*   top_i    = (int*)alloc((size_t)N_TOK * 2 * 4);
  float* top_w    = (float*)alloc((size_t)N_TOK * 2 * 4);
  int*   rowlist  = (int*)alloc((size_t)2 * N_TOK * 4);
  float* wlist    = (float*)alloc((size_t)2 * N_TOK * 4);
  float* probs_tok = (float*)alloc((size_t)N_TOK * NEXP * 4);

  // zero the main output (epilogues accumulate via atomicAdd)
  hipMemsetAsync(out, 0, (size_t)N_TOK * CDIM * 4, stream);

  // fused weight precast f32 -> bf16 (6 tensors, one launch)
  Cast6 c6;
  c6.src[0] = egw; c6.dst[0] = egw_b;
  c6.src[1] = euw; c6.dst[1] = euw_b;
  c6.src[2] = edw; c6.dst[2] = edw_b;
  c6.src[3] = sgw; c6.dst[3] = sgw_b;
  c6.src[4] = suw; c6.dst[4] = suw_b;
  c6.src[5] = sdw; c6.dst[5] = sdw_b;
  int ew_blk = (int)(EW / 1024), sw_blk = (int)(SW / 1024);
  c6.start[0] = 0;
  c6.start[1] = ew_blk;     c6.start[2] = 2 * ew_blk; c6.start[3] = 3 * ew_blk;
  c6.start[4] = 3 * ew_blk + sw_blk;
  c6.start[5] = 3 * ew_blk + 2 * sw_blk;
  c6.start[6] = 3 * ew_blk + 3 * sw_blk;
  moe_cast6<<<c6.start[6], 256, 0, stream>>>(c6);

  moe_gating<<<1024, 256, 0, stream>>>(x, gw, top_i, top_w, probs_tok, xb);
  moe_reduce<<<NEXP, 256, 0, stream>>>(probs_tok, top_i, cnts, probs_sum);
  moe_prefix_aux<<<1, 64, 0, stream>>>(cnts, offs, cursors, probs_sum, out + (size_t)N_TOK * CDIM);
  moe_scatter<<<16, 256, 0, stream>>>(top_i, top_w, offs, cursors, rowlist, wlist);

  // gate+up: x = n-panel (43, fastest), y = m-block (32), z = 8 routed + 1 shared
  moe_gu<<<dim3(HDIM / 64, N_TOK / 128, NEXP + 1), 256, 0, stream>>>(
      xb, egw_b, euw_b, sgw_b, suw_b, h, rowlist, offs, cnts);
  // down: x = n-panel (8, BN=128), y = m-block, z = 8 routed + 1 shared; accumulates into out
  moe_down<<<dim3(CDIM / 128, N_TOK / 128, NEXP + 1), 256, 0, stream>>>(
      h, edw_b, sdw_b, out, wlist, rowlist, offs, cnts);
}